// Round 12
// baseline (82.841 us; speedup 1.0000x reference)
//
#include <hip/hip_runtime.h>
#include <hip/hip_bf16.h>
#include <math.h>

#define B_ 32
#define T_ 2048
#define H_ 1024
#define DOUT_ 128

#define RW_ 32                     // rows per wave (fused pass)
#define WPB_ 4                     // waves per block
#define FBLK_ (T_ / RW_ / WPB_)    // 16 blocks per batch
#define NPART_ FBLK_               // one merged partial per block

#define JC_ 16                     // j-chunks for output GEMV
#define JCH_ (2 * H_ / JC_)        // 128 j per chunk

typedef float f4 __attribute__((ext_vector_type(4)));

// ---------------------------------------------------------------------------
// Kernel 1: v[b,h] = dot(W_score[h,:], h_t[b,:]).
// grid = H blocks x 256 thr (4 waves); wave w handles batches 8w..8w+7.
// Block 0 also zeroes the out-stage tickets (stream-ordered before kernel 3).
// ---------------------------------------------------------------------------
__global__ __launch_bounds__(256) void compute_v_kernel(
    const float* __restrict__ hs, const float* __restrict__ Wscore,
    float* __restrict__ v, unsigned* __restrict__ tickets) {
  const int h = blockIdx.x;
  const int tid = threadIdx.x;
  if (h == 0 && tid < B_) tickets[tid] = 0u;  // per-launch reset
  const int wave = tid >> 6, lane = tid & 63;
  const f4* wrow = (const f4*)(Wscore + (size_t)h * H_);
  f4 w4[4];
#pragma unroll
  for (int i = 0; i < 4; ++i) w4[i] = wrow[lane + 64 * i];
#pragma unroll
  for (int bb = 0; bb < 8; ++bb) {
    const int b = wave * 8 + bb;
    const f4* ht = (const f4*)(hs + ((size_t)b * T_ + (T_ - 1)) * H_);
    float acc = 0.f;
#pragma unroll
    for (int i = 0; i < 4; ++i) {
      f4 a = ht[lane + 64 * i];
      acc += a.x * w4[i].x + a.y * w4[i].y + a.z * w4[i].z + a.w * w4[i].w;
    }
#pragma unroll
    for (int off = 32; off > 0; off >>= 1) acc += __shfl_down(acc, off);
    if (lane == 0) v[b * H_ + h] = acc;
  }
}

// ---------------------------------------------------------------------------
// Fused pass helpers: wave-private register-resident online softmax + ctx.
// Lane l owns f4 slots {l, l+64, l+128, l+192} of each 1024-float row.
// ---------------------------------------------------------------------------
__device__ __forceinline__ float dot16(const f4 (&A)[4], const f4 (&V)[4]) {
  float p = 0.f;
#pragma unroll
  for (int i = 0; i < 4; ++i)
    p += A[i].x * V[i].x + A[i].y * V[i].y + A[i].z * V[i].z + A[i].w * V[i].w;
  return p;
}

// defer-max (T13): rescale only when the new score exceeds m by >8; weights
// then bounded by e^8 — exact after the final merge renormalization.
__device__ __forceinline__ void upd_row(float p, const f4 (&R)[4], float& m,
                                        float& lsum, f4 (&acc)[4]) {
  if (p > m + 8.f) {  // wave-uniform (p is reduced), no divergence
    const float sc = __expf(m - p);
    lsum *= sc;
#pragma unroll
    for (int i = 0; i < 4; ++i) acc[i] *= sc;
    m = p;
  }
  const float w = __expf(p - m);
  lsum += w;
#pragma unroll
  for (int i = 0; i < 4; ++i) {
    acc[i].x = fmaf(w, R[i].x, acc[i].x);
    acc[i].y = fmaf(w, R[i].y, acc[i].y);
    acc[i].z = fmaf(w, R[i].z, acc[i].z);
    acc[i].w = fmaf(w, R[i].w, acc[i].w);
  }
}

// plain cached loads (nt: R9/R10 showed no benefit).
#define LOADROW(dst, r)                                  \
  _Pragma("unroll") for (int i = 0; i < 4; ++i) dst[i] = \
      rp[(size_t)(r) * 256 + lane + 64 * i];

// ---------------------------------------------------------------------------
// Kernel 2 (fused, one pass over hs): wave-per-32-rows in registers, no
// barriers in the streaming loop; two row buffers (A,B rotate); 4
// wave-partials merged in-block via LDS -> ONE (m,l,ctx[1024]) per block.
// Byte-identical to R11's version.
// ---------------------------------------------------------------------------
__global__ __launch_bounds__(256) void fused_score_ctx_kernel(
    const float* __restrict__ hs, const float* __restrict__ v,
    float* __restrict__ pm, float* __restrict__ pl,
    float* __restrict__ pctx) {
  const int b = blockIdx.y;
  const int wave = threadIdx.x >> 6;
  const int lane = threadIdx.x & 63;
  const int wv = blockIdx.x * WPB_ + wave;  // 0..63 (wave's row group)

  const f4* vb = (const f4*)(v + (size_t)b * H_);
  f4 vreg[4];
#pragma unroll
  for (int i = 0; i < 4; ++i) vreg[i] = vb[lane + 64 * i];

  const f4* rp = (const f4*)(hs + ((size_t)b * T_ + (size_t)wv * RW_) * H_);

  f4 A[4], Bv[4];
  LOADROW(A, 0);
  LOADROW(Bv, 1);

  float m = -1e30f, lsum = 0.f;
  f4 acc[4] = {{0, 0, 0, 0}, {0, 0, 0, 0}, {0, 0, 0, 0}, {0, 0, 0, 0}};

#pragma unroll
  for (int rr = 0; rr < RW_; rr += 2) {
    float pA = dot16(A, vreg), pB = dot16(Bv, vreg);
#pragma unroll
    for (int off = 32; off > 0; off >>= 1) {  // two interleaved chains
      pA += __shfl_xor(pA, off);
      pB += __shfl_xor(pB, off);
    }
    upd_row(pA, A, m, lsum, acc);
    if (rr + 2 < RW_) LOADROW(A, rr + 2);  // refill A while B is consumed
    upd_row(pB, Bv, m, lsum, acc);
    if (rr + 3 < RW_) LOADROW(Bv, rr + 3);
  }

  // in-block merge of the 4 wave-partials (16.4 KB LDS)
  __shared__ f4 sacc[WPB_][256];
  __shared__ float sm[WPB_], sl[WPB_];
#pragma unroll
  for (int i = 0; i < 4; ++i) sacc[wave][lane + 64 * i] = acc[i];
  if (lane == 0) { sm[wave] = m; sl[wave] = lsum; }
  __syncthreads();

  const int tid = threadIdx.x;
  float Mb = fmaxf(fmaxf(sm[0], sm[1]), fmaxf(sm[2], sm[3]));
  float f0 = __expf(sm[0] - Mb), f1 = __expf(sm[1] - Mb);
  float f2 = __expf(sm[2] - Mb), f3 = __expf(sm[3] - Mb);
  float Lb = sl[0] * f0 + sl[1] * f1 + sl[2] * f2 + sl[3] * f3;
  f4 r = f0 * sacc[0][tid] + f1 * sacc[1][tid] + f2 * sacc[2][tid] +
         f3 * sacc[3][tid];

  const int pidx = b * NPART_ + blockIdx.x;
  if (tid == 0) { pm[pidx] = Mb; pl[pidx] = Lb; }
  ((f4*)pctx)[(size_t)pidx * 256 + tid] = r;
}

// ---------------------------------------------------------------------------
// Kernel 3: merge partials + output GEMV partials + LAST-ARRIVER finish.
// grid = (B, JC) = 512 blocks x 128 thr. Each block writes opart[b][jc][:];
// the 16th arriver per batch (ticket) re-reads all 16 slices in fixed order
// and writes out[b,:] = tanh(sum). Bit-deterministic; no residency assumed.
// ---------------------------------------------------------------------------
__global__ __launch_bounds__(128) void out_partial_kernel(
    const float* __restrict__ pm, const float* __restrict__ pl,
    const float* __restrict__ pctx, const float* __restrict__ hs,
    const float* __restrict__ Wout, float* __restrict__ opart,
    unsigned* __restrict__ tickets, float* __restrict__ out) {
  const int b = blockIdx.x;
  const int jc = blockIdx.y;
  const int d = threadIdx.x;  // 0..127
  __shared__ float pre[JCH_];
  __shared__ int sdone;
  if (jc < 8) {
    const float* pmb = pm + b * NPART_;
    const float* plb = pl + b * NPART_;
    float M = -1e30f;
#pragma unroll
    for (int j = 0; j < NPART_; ++j) M = fmaxf(M, pmb[j]);
    float L = 0.f;
#pragma unroll
    for (int j = 0; j < NPART_; ++j) L += plb[j] * __expf(pmb[j] - M);
    float a = 0.f;
    const int h = jc * JCH_ + d;
#pragma unroll 4
    for (int j = 0; j < NPART_; ++j)
      a += __expf(pmb[j] - M) * pctx[((size_t)(b * NPART_ + j)) * H_ + h];
    pre[d] = a / L;
  } else {
    pre[d] = hs[((size_t)b * T_ + (T_ - 1)) * H_ + (jc - 8) * JCH_ + d];
  }
  __syncthreads();
  float acc = 0.f;
#pragma unroll 8
  for (int i = 0; i < JCH_; ++i)
    acc += pre[i] * Wout[((size_t)(jc * JCH_ + i)) * DOUT_ + d];
  opart[((size_t)b * JC_ + jc) * DOUT_ + d] = acc;

  // release our slice, take a ticket
  __threadfence();
  if (d == 0) {
    unsigned old = atomicAdd(&tickets[b], 1u);
    sdone = (old == JC_ - 1u) ? 1 : 0;
  }
  __syncthreads();
  if (sdone) {
    __threadfence();  // acquire: all 16 slices visible
    float s = 0.f;
#pragma unroll
    for (int j = 0; j < JC_; ++j)
      s += opart[((size_t)b * JC_ + j) * DOUT_ + d];
    out[(size_t)b * DOUT_ + d] = tanhf(s);
  }
}

extern "C" void kernel_launch(void* const* d_in, const int* in_sizes, int n_in,
                              void* d_out, int out_size, void* d_ws, size_t ws_size,
                              hipStream_t stream) {
  const float* hs = (const float*)d_in[0];      // (B, T, H)
  const float* Wscore = (const float*)d_in[1];  // (H, H)
  const float* Wout = (const float*)d_in[2];    // (2H, DOUT)
  float* out = (float*)d_out;                   // (B, DOUT)

  float* ws = (float*)d_ws;
  float* v = ws;                                // B*H        = 32768
  float* pm = v + B_ * H_;                      // B*16       = 512
  float* pl = pm + B_ * NPART_;                 // B*16       = 512
  float* pctx = pl + B_ * NPART_;               // B*16*H     = 524288
  float* opart = pctx + (size_t)B_ * NPART_ * H_;  // B*JC*DOUT = 65536
  unsigned* tickets = (unsigned*)(opart + (size_t)B_ * JC_ * DOUT_);  // B_

  compute_v_kernel<<<dim3(H_), 256, 0, stream>>>(hs, Wscore, v, tickets);
  fused_score_ctx_kernel<<<dim3(FBLK_, B_), 256, 0, stream>>>(hs, v, pm, pl, pctx);
  out_partial_kernel<<<dim3(B_, JC_), 128, 0, stream>>>(pm, pl, pctx, hs, Wout,
                                                        opart, tickets, out);
}

// Round 13
// 68.363 us; speedup vs baseline: 1.2118x; 1.2118x over previous
//
#include <hip/hip_runtime.h>
#include <hip/hip_bf16.h>
#include <math.h>

#define B_ 32
#define T_ 2048
#define H_ 1024
#define DOUT_ 128

#define RW_ 32                     // rows per wave (fused pass)
#define WPB_ 4                     // waves per block
#define FBLK_ (T_ / RW_ / WPB_)    // 16 blocks per batch
#define NPART_ FBLK_               // one merged partial per block

#define JC_ 16                     // j-chunks for output GEMV
#define JCH_ (2 * H_ / JC_)        // 128 j per chunk

#define HR_ 4                      // W rows per block in compute_v

typedef float f4 __attribute__((ext_vector_type(4)));

// ---------------------------------------------------------------------------
// Kernel 1: v[b,h] = dot(W_score[h,:], h_t[b,:]).
// grid = H/HR_ = 256 blocks x 256 thr; each block owns HR_=4 W-rows in
// registers, so the h_t set (128 KB) is re-read 256x not 1024x (L2 traffic /4).
// ---------------------------------------------------------------------------
__global__ __launch_bounds__(256) void compute_v_kernel(
    const float* __restrict__ hs, const float* __restrict__ Wscore,
    float* __restrict__ v) {
  const int h0 = blockIdx.x * HR_;
  const int tid = threadIdx.x;
  const int wave = tid >> 6, lane = tid & 63;
  f4 w4[HR_][4];
#pragma unroll
  for (int r = 0; r < HR_; ++r) {
    const f4* wrow = (const f4*)(Wscore + (size_t)(h0 + r) * H_);
#pragma unroll
    for (int i = 0; i < 4; ++i) w4[r][i] = wrow[lane + 64 * i];
  }
#pragma unroll
  for (int bb = 0; bb < 8; ++bb) {
    const int b = wave * 8 + bb;
    const f4* ht = (const f4*)(hs + ((size_t)b * T_ + (T_ - 1)) * H_);
    f4 a[4];
#pragma unroll
    for (int i = 0; i < 4; ++i) a[i] = ht[lane + 64 * i];
#pragma unroll
    for (int r = 0; r < HR_; ++r) {
      float acc = 0.f;
#pragma unroll
      for (int i = 0; i < 4; ++i)
        acc += a[i].x * w4[r][i].x + a[i].y * w4[r][i].y +
               a[i].z * w4[r][i].z + a[i].w * w4[r][i].w;
#pragma unroll
      for (int off = 32; off > 0; off >>= 1) acc += __shfl_down(acc, off);
      if (lane == 0) v[b * H_ + h0 + r] = acc;
    }
  }
}

// ---------------------------------------------------------------------------
// Fused pass helpers: wave-private register-resident online softmax + ctx.
// Lane l owns f4 slots {l, l+64, l+128, l+192} of each 1024-float row.
// ---------------------------------------------------------------------------
__device__ __forceinline__ float dot16(const f4 (&A)[4], const f4 (&V)[4]) {
  float p = 0.f;
#pragma unroll
  for (int i = 0; i < 4; ++i)
    p += A[i].x * V[i].x + A[i].y * V[i].y + A[i].z * V[i].z + A[i].w * V[i].w;
  return p;
}

// defer-max (T13): rescale only when the new score exceeds m by >8; weights
// then bounded by e^8 — exact after the final merge renormalization.
__device__ __forceinline__ void upd_row(float p, const f4 (&R)[4], float& m,
                                        float& lsum, f4 (&acc)[4]) {
  if (p > m + 8.f) {  // wave-uniform (p is reduced), no divergence
    const float sc = __expf(m - p);
    lsum *= sc;
#pragma unroll
    for (int i = 0; i < 4; ++i) acc[i] *= sc;
    m = p;
  }
  const float w = __expf(p - m);
  lsum += w;
#pragma unroll
  for (int i = 0; i < 4; ++i) {
    acc[i].x = fmaf(w, R[i].x, acc[i].x);
    acc[i].y = fmaf(w, R[i].y, acc[i].y);
    acc[i].z = fmaf(w, R[i].z, acc[i].z);
    acc[i].w = fmaf(w, R[i].w, acc[i].w);
  }
}

// plain cached loads (nt: R9/R10 showed no benefit).
#define LOADROW(dst, r)                                  \
  _Pragma("unroll") for (int i = 0; i < 4; ++i) dst[i] = \
      rp[(size_t)(r) * 256 + lane + 64 * i];

// ---------------------------------------------------------------------------
// Kernel 2 (fused, one pass over hs): wave-per-32-rows in registers, no
// barriers in the streaming loop; two row buffers (A,B rotate); 4
// wave-partials merged in-block via LDS -> ONE (m,l,ctx[1024]) per block.
// Byte-identical to R11's version.
// ---------------------------------------------------------------------------
__global__ __launch_bounds__(256) void fused_score_ctx_kernel(
    const float* __restrict__ hs, const float* __restrict__ v,
    float* __restrict__ pm, float* __restrict__ pl,
    float* __restrict__ pctx) {
  const int b = blockIdx.y;
  const int wave = threadIdx.x >> 6;
  const int lane = threadIdx.x & 63;
  const int wv = blockIdx.x * WPB_ + wave;  // 0..63 (wave's row group)

  const f4* vb = (const f4*)(v + (size_t)b * H_);
  f4 vreg[4];
#pragma unroll
  for (int i = 0; i < 4; ++i) vreg[i] = vb[lane + 64 * i];

  const f4* rp = (const f4*)(hs + ((size_t)b * T_ + (size_t)wv * RW_) * H_);

  f4 A[4], Bv[4];
  LOADROW(A, 0);
  LOADROW(Bv, 1);

  float m = -1e30f, lsum = 0.f;
  f4 acc[4] = {{0, 0, 0, 0}, {0, 0, 0, 0}, {0, 0, 0, 0}, {0, 0, 0, 0}};

#pragma unroll
  for (int rr = 0; rr < RW_; rr += 2) {
    float pA = dot16(A, vreg), pB = dot16(Bv, vreg);
#pragma unroll
    for (int off = 32; off > 0; off >>= 1) {  // two interleaved chains
      pA += __shfl_xor(pA, off);
      pB += __shfl_xor(pB, off);
    }
    upd_row(pA, A, m, lsum, acc);
    if (rr + 2 < RW_) LOADROW(A, rr + 2);  // refill A while B is consumed
    upd_row(pB, Bv, m, lsum, acc);
    if (rr + 3 < RW_) LOADROW(Bv, rr + 3);
  }

  // in-block merge of the 4 wave-partials (16.4 KB LDS)
  __shared__ f4 sacc[WPB_][256];
  __shared__ float sm[WPB_], sl[WPB_];
#pragma unroll
  for (int i = 0; i < 4; ++i) sacc[wave][lane + 64 * i] = acc[i];
  if (lane == 0) { sm[wave] = m; sl[wave] = lsum; }
  __syncthreads();

  const int tid = threadIdx.x;
  float Mb = fmaxf(fmaxf(sm[0], sm[1]), fmaxf(sm[2], sm[3]));
  float f0 = __expf(sm[0] - Mb), f1 = __expf(sm[1] - Mb);
  float f2 = __expf(sm[2] - Mb), f3 = __expf(sm[3] - Mb);
  float Lb = sl[0] * f0 + sl[1] * f1 + sl[2] * f2 + sl[3] * f3;
  f4 r = f0 * sacc[0][tid] + f1 * sacc[1][tid] + f2 * sacc[2][tid] +
         f3 * sacc[3][tid];

  const int pidx = b * NPART_ + blockIdx.x;
  if (tid == 0) { pm[pidx] = Mb; pl[pidx] = Lb; }
  ((f4*)pctx)[(size_t)pidx * 256 + tid] = r;
}

// ---------------------------------------------------------------------------
// Kernel 3: merge partials + output GEMV partials, fused.
// grid = (B, JC) = 512 blocks x 128 thr. jc<8: merge the needed 128-float
// ctx slice from the 16 block-partials; jc>=8: slice of h_t. Then
// opart[b,jc,d] = sum_i pre[i] * Wout[jc*128+i, d].
// ---------------------------------------------------------------------------
__global__ __launch_bounds__(128) void out_partial_kernel(
    const float* __restrict__ pm, const float* __restrict__ pl,
    const float* __restrict__ pctx, const float* __restrict__ hs,
    const float* __restrict__ Wout, float* __restrict__ opart) {
  const int b = blockIdx.x;
  const int jc = blockIdx.y;
  const int d = threadIdx.x;  // 0..127
  __shared__ float pre[JCH_];
  if (jc < 8) {
    const float* pmb = pm + b * NPART_;
    const float* plb = pl + b * NPART_;
    float M = -1e30f;
#pragma unroll
    for (int j = 0; j < NPART_; ++j) M = fmaxf(M, pmb[j]);
    float L = 0.f;
#pragma unroll
    for (int j = 0; j < NPART_; ++j) L += plb[j] * __expf(pmb[j] - M);
    float a = 0.f;
    const int h = jc * JCH_ + d;
#pragma unroll 4
    for (int j = 0; j < NPART_; ++j)
      a += __expf(pmb[j] - M) * pctx[((size_t)(b * NPART_ + j)) * H_ + h];
    pre[d] = a / L;
  } else {
    pre[d] = hs[((size_t)b * T_ + (T_ - 1)) * H_ + (jc - 8) * JCH_ + d];
  }
  __syncthreads();
  float acc = 0.f;
#pragma unroll 8
  for (int i = 0; i < JCH_; ++i)
    acc += pre[i] * Wout[((size_t)(jc * JCH_ + i)) * DOUT_ + d];
  opart[((size_t)b * JC_ + jc) * DOUT_ + d] = acc;
}

// ---------------------------------------------------------------------------
// Kernel 4: out[b,d] = tanh( sum_jc opart[b,jc,d] )
// ---------------------------------------------------------------------------
__global__ __launch_bounds__(128) void out_reduce_kernel(
    const float* __restrict__ opart, float* __restrict__ out) {
  const int b = blockIdx.x;
  const int d = threadIdx.x;
  float acc = 0.f;
#pragma unroll
  for (int jc = 0; jc < JC_; ++jc)
    acc += opart[((size_t)b * JC_ + jc) * DOUT_ + d];
  out[(size_t)b * DOUT_ + d] = tanhf(acc);
}

extern "C" void kernel_launch(void* const* d_in, const int* in_sizes, int n_in,
                              void* d_out, int out_size, void* d_ws, size_t ws_size,
                              hipStream_t stream) {
  const float* hs = (const float*)d_in[0];      // (B, T, H)
  const float* Wscore = (const float*)d_in[1];  // (H, H)
  const float* Wout = (const float*)d_in[2];    // (2H, DOUT)
  float* out = (float*)d_out;                   // (B, DOUT)

  float* ws = (float*)d_ws;
  float* v = ws;                                // B*H        = 32768
  float* pm = v + B_ * H_;                      // B*16       = 512
  float* pl = pm + B_ * NPART_;                 // B*16       = 512
  float* pctx = pl + B_ * NPART_;               // B*16*H     = 524288
  float* opart = pctx + (size_t)B_ * NPART_ * H_;  // B*JC*DOUT = 65536

  compute_v_kernel<<<dim3(H_ / HR_), 256, 0, stream>>>(hs, Wscore, v);
  fused_score_ctx_kernel<<<dim3(FBLK_, B_), 256, 0, stream>>>(hs, v, pm, pl, pctx);
  out_partial_kernel<<<dim3(B_, JC_), 128, 0, stream>>>(pm, pl, pctx, hs, Wout, opart);
  out_reduce_kernel<<<dim3(B_), 128, 0, stream>>>(opart, out);
}

// Round 14
// 65.754 us; speedup vs baseline: 1.2599x; 1.0397x over previous
//
#include <hip/hip_runtime.h>
#include <hip/hip_bf16.h>
#include <math.h>

#define B_ 32
#define T_ 2048
#define H_ 1024
#define DOUT_ 128

#define RW_ 32                     // rows per wave (fused pass)
#define WPB_ 4                     // waves per block
#define FBLK_ (T_ / RW_ / WPB_)    // 16 blocks per batch
#define NPART_ FBLK_               // one merged partial per block

#define JC_ 16                     // j-chunks for output GEMV
#define JCH_ (2 * H_ / JC_)        // 128 j per chunk

typedef float f4 __attribute__((ext_vector_type(4)));

// ---------------------------------------------------------------------------
// Kernel 1: v[b,h] = dot(W_score[h,:], h_t[b,:]).
// grid = H blocks x 256 thr (4 waves); wave w handles batches 8w..8w+7.
// (R11 version — R13's HR=4 variant was neutral-negative.)
// ---------------------------------------------------------------------------
__global__ __launch_bounds__(256) void compute_v_kernel(
    const float* __restrict__ hs, const float* __restrict__ Wscore,
    float* __restrict__ v) {
  const int h = blockIdx.x;
  const int tid = threadIdx.x;
  const int wave = tid >> 6, lane = tid & 63;
  const f4* wrow = (const f4*)(Wscore + (size_t)h * H_);
  f4 w4[4];
#pragma unroll
  for (int i = 0; i < 4; ++i) w4[i] = wrow[lane + 64 * i];
#pragma unroll
  for (int bb = 0; bb < 8; ++bb) {
    const int b = wave * 8 + bb;
    const f4* ht = (const f4*)(hs + ((size_t)b * T_ + (T_ - 1)) * H_);
    float acc = 0.f;
#pragma unroll
    for (int i = 0; i < 4; ++i) {
      f4 a = ht[lane + 64 * i];
      acc += a.x * w4[i].x + a.y * w4[i].y + a.z * w4[i].z + a.w * w4[i].w;
    }
#pragma unroll
    for (int off = 32; off > 0; off >>= 1) acc += __shfl_down(acc, off);
    if (lane == 0) v[b * H_ + h] = acc;
  }
}

// ---------------------------------------------------------------------------
// Fused pass helpers: wave-private register-resident online softmax + ctx.
// Lane l owns f4 slots {l, l+64, l+128, l+192} of each 1024-float row.
// ---------------------------------------------------------------------------
__device__ __forceinline__ float dot16(const f4 (&A)[4], const f4 (&V)[4]) {
  float p = 0.f;
#pragma unroll
  for (int i = 0; i < 4; ++i)
    p += A[i].x * V[i].x + A[i].y * V[i].y + A[i].z * V[i].z + A[i].w * V[i].w;
  return p;
}

// defer-max (T13): rescale only when the new score exceeds m by >8; weights
// then bounded by e^8 — exact after the final merge renormalization.
__device__ __forceinline__ void upd_row(float p, const f4 (&R)[4], float& m,
                                        float& lsum, f4 (&acc)[4]) {
  if (p > m + 8.f) {  // wave-uniform (p is reduced), no divergence
    const float sc = __expf(m - p);
    lsum *= sc;
#pragma unroll
    for (int i = 0; i < 4; ++i) acc[i] *= sc;
    m = p;
  }
  const float w = __expf(p - m);
  lsum += w;
#pragma unroll
  for (int i = 0; i < 4; ++i) {
    acc[i].x = fmaf(w, R[i].x, acc[i].x);
    acc[i].y = fmaf(w, R[i].y, acc[i].y);
    acc[i].z = fmaf(w, R[i].z, acc[i].z);
    acc[i].w = fmaf(w, R[i].w, acc[i].w);
  }
}

// plain cached loads (nt: R9/R10 showed no benefit).
#define LOADROW(dst, r)                                  \
  _Pragma("unroll") for (int i = 0; i < 4; ++i) dst[i] = \
      rp[(size_t)(r) * 256 + lane + 64 * i];

// ---------------------------------------------------------------------------
// Kernel 2 (fused, one pass over hs): wave-per-32-rows in registers, no
// barriers in the streaming loop; two row buffers (A,B rotate); 4
// wave-partials merged in-block via LDS -> ONE (m,l,ctx[1024]) per block.
// ---------------------------------------------------------------------------
__global__ __launch_bounds__(256) void fused_score_ctx_kernel(
    const float* __restrict__ hs, const float* __restrict__ v,
    float* __restrict__ pm, float* __restrict__ pl,
    float* __restrict__ pctx) {
  const int b = blockIdx.y;
  const int wave = threadIdx.x >> 6;
  const int lane = threadIdx.x & 63;
  const int wv = blockIdx.x * WPB_ + wave;  // 0..63 (wave's row group)

  const f4* vb = (const f4*)(v + (size_t)b * H_);
  f4 vreg[4];
#pragma unroll
  for (int i = 0; i < 4; ++i) vreg[i] = vb[lane + 64 * i];

  const f4* rp = (const f4*)(hs + ((size_t)b * T_ + (size_t)wv * RW_) * H_);

  f4 A[4], Bv[4];
  LOADROW(A, 0);
  LOADROW(Bv, 1);

  float m = -1e30f, lsum = 0.f;
  f4 acc[4] = {{0, 0, 0, 0}, {0, 0, 0, 0}, {0, 0, 0, 0}, {0, 0, 0, 0}};

#pragma unroll
  for (int rr = 0; rr < RW_; rr += 2) {
    float pA = dot16(A, vreg), pB = dot16(Bv, vreg);
#pragma unroll
    for (int off = 32; off > 0; off >>= 1) {  // two interleaved chains
      pA += __shfl_xor(pA, off);
      pB += __shfl_xor(pB, off);
    }
    upd_row(pA, A, m, lsum, acc);
    if (rr + 2 < RW_) LOADROW(A, rr + 2);  // refill A while B is consumed
    upd_row(pB, Bv, m, lsum, acc);
    if (rr + 3 < RW_) LOADROW(Bv, rr + 3);
  }

  // in-block merge of the 4 wave-partials (16.4 KB LDS)
  __shared__ f4 sacc[WPB_][256];
  __shared__ float sm[WPB_], sl[WPB_];
#pragma unroll
  for (int i = 0; i < 4; ++i) sacc[wave][lane + 64 * i] = acc[i];
  if (lane == 0) { sm[wave] = m; sl[wave] = lsum; }
  __syncthreads();

  const int tid = threadIdx.x;
  float Mb = fmaxf(fmaxf(sm[0], sm[1]), fmaxf(sm[2], sm[3]));
  float f0 = __expf(sm[0] - Mb), f1 = __expf(sm[1] - Mb);
  float f2 = __expf(sm[2] - Mb), f3 = __expf(sm[3] - Mb);
  float Lb = sl[0] * f0 + sl[1] * f1 + sl[2] * f2 + sl[3] * f3;
  f4 r = f0 * sacc[0][tid] + f1 * sacc[1][tid] + f2 * sacc[2][tid] +
         f3 * sacc[3][tid];

  const int pidx = b * NPART_ + blockIdx.x;
  if (tid == 0) { pm[pidx] = Mb; pl[pidx] = Lb; }
  ((f4*)pctx)[(size_t)pidx * 256 + tid] = r;
}

// ---------------------------------------------------------------------------
// Kernel 3: merge partials + output GEMV partials, fused.
// grid = (B, JC) = 512 blocks x 128 thr. jc<8: merge the needed 128-float
// ctx slice from the 16 block-partials; jc>=8: slice of h_t. Then
// opart[b,jc,d] = sum_i pre[i] * Wout[jc*128+i, d].
// ---------------------------------------------------------------------------
__global__ __launch_bounds__(128) void out_partial_kernel(
    const float* __restrict__ pm, const float* __restrict__ pl,
    const float* __restrict__ pctx, const float* __restrict__ hs,
    const float* __restrict__ Wout, float* __restrict__ opart) {
  const int b = blockIdx.x;
  const int jc = blockIdx.y;
  const int d = threadIdx.x;  // 0..127
  __shared__ float pre[JCH_];
  if (jc < 8) {
    const float* pmb = pm + b * NPART_;
    const float* plb = pl + b * NPART_;
    float M = -1e30f;
#pragma unroll
    for (int j = 0; j < NPART_; ++j) M = fmaxf(M, pmb[j]);
    float L = 0.f;
#pragma unroll
    for (int j = 0; j < NPART_; ++j) L += plb[j] * __expf(pmb[j] - M);
    float a = 0.f;
    const int h = jc * JCH_ + d;
#pragma unroll 4
    for (int j = 0; j < NPART_; ++j)
      a += __expf(pmb[j] - M) * pctx[((size_t)(b * NPART_ + j)) * H_ + h];
    pre[d] = a / L;
  } else {
    pre[d] = hs[((size_t)b * T_ + (T_ - 1)) * H_ + (jc - 8) * JCH_ + d];
  }
  __syncthreads();
  float acc = 0.f;
#pragma unroll 8
  for (int i = 0; i < JCH_; ++i)
    acc += pre[i] * Wout[((size_t)(jc * JCH_ + i)) * DOUT_ + d];
  opart[((size_t)b * JC_ + jc) * DOUT_ + d] = acc;
}

// ---------------------------------------------------------------------------
// Kernel 4: out[b,d] = tanh( sum_jc opart[b,jc,d] )
// ---------------------------------------------------------------------------
__global__ __launch_bounds__(128) void out_reduce_kernel(
    const float* __restrict__ opart, float* __restrict__ out) {
  const int b = blockIdx.x;
  const int d = threadIdx.x;
  float acc = 0.f;
#pragma unroll
  for (int jc = 0; jc < JC_; ++jc)
    acc += opart[((size_t)b * JC_ + jc) * DOUT_ + d];
  out[(size_t)b * DOUT_ + d] = tanhf(acc);
}

extern "C" void kernel_launch(void* const* d_in, const int* in_sizes, int n_in,
                              void* d_out, int out_size, void* d_ws, size_t ws_size,
                              hipStream_t stream) {
  const float* hs = (const float*)d_in[0];      // (B, T, H)
  const float* Wscore = (const float*)d_in[1];  // (H, H)
  const float* Wout = (const float*)d_in[2];    // (2H, DOUT)
  float* out = (float*)d_out;                   // (B, DOUT)

  float* ws = (float*)d_ws;
  float* v = ws;                                // B*H        = 32768
  float* pm = v + B_ * H_;                      // B*16       = 512
  float* pl = pm + B_ * NPART_;                 // B*16       = 512
  float* pctx = pl + B_ * NPART_;               // B*16*H     = 524288
  float* opart = pctx + (size_t)B_ * NPART_ * H_;  // B*JC*DOUT = 65536

  compute_v_kernel<<<dim3(H_), 256, 0, stream>>>(hs, Wscore, v);
  fused_score_ctx_kernel<<<dim3(FBLK_, B_), 256, 0, stream>>>(hs, v, pm, pl, pctx);
  out_partial_kernel<<<dim3(B_, JC_), 128, 0, stream>>>(pm, pl, pctx, hs, Wout, opart);
  out_reduce_kernel<<<dim3(B_), 128, 0, stream>>>(opart, out);
}

// Round 15
// 61.058 us; speedup vs baseline: 1.3568x; 1.0769x over previous
//
#include <hip/hip_runtime.h>
#include <hip/hip_bf16.h>
#include <math.h>

#define B_ 32
#define T_ 2048
#define H_ 1024
#define DOUT_ 128

#define RW_ 32                     // rows per wave (fused pass)
#define WPB_ 4                     // waves per block
#define BROWS_ (RW_ * WPB_)        // 128 rows per block (shared window)
#define FBLK_ (T_ / BROWS_)        // 16 blocks per batch
#define NPART_ FBLK_               // one merged partial per block

#define JC_ 16                     // j-chunks for output GEMV
#define JCH_ (2 * H_ / JC_)        // 128 j per chunk

typedef float f4 __attribute__((ext_vector_type(4)));

// ---------------------------------------------------------------------------
// Kernel 1: v[b,h] = dot(W_score[h,:], h_t[b,:]).
// grid = H blocks x 256 thr (4 waves); wave w handles batches 8w..8w+7.
// ---------------------------------------------------------------------------
__global__ __launch_bounds__(256) void compute_v_kernel(
    const float* __restrict__ hs, const float* __restrict__ Wscore,
    float* __restrict__ v) {
  const int h = blockIdx.x;
  const int tid = threadIdx.x;
  const int wave = tid >> 6, lane = tid & 63;
  const f4* wrow = (const f4*)(Wscore + (size_t)h * H_);
  f4 w4[4];
#pragma unroll
  for (int i = 0; i < 4; ++i) w4[i] = wrow[lane + 64 * i];
#pragma unroll
  for (int bb = 0; bb < 8; ++bb) {
    const int b = wave * 8 + bb;
    const f4* ht = (const f4*)(hs + ((size_t)b * T_ + (T_ - 1)) * H_);
    float acc = 0.f;
#pragma unroll
    for (int i = 0; i < 4; ++i) {
      f4 a = ht[lane + 64 * i];
      acc += a.x * w4[i].x + a.y * w4[i].y + a.z * w4[i].z + a.w * w4[i].w;
    }
#pragma unroll
    for (int off = 32; off > 0; off >>= 1) acc += __shfl_down(acc, off);
    if (lane == 0) v[b * H_ + h] = acc;
  }
}

// ---------------------------------------------------------------------------
// Fused pass helpers: wave-private register-resident online softmax + ctx.
// Lane l owns f4 slots {l, l+64, l+128, l+192} of each 1024-float row.
// ---------------------------------------------------------------------------
__device__ __forceinline__ float dot16(const f4 (&A)[4], const f4 (&V)[4]) {
  float p = 0.f;
#pragma unroll
  for (int i = 0; i < 4; ++i)
    p += A[i].x * V[i].x + A[i].y * V[i].y + A[i].z * V[i].z + A[i].w * V[i].w;
  return p;
}

// defer-max (T13): rescale only when the new score exceeds m by >8; weights
// then bounded by e^8 — exact after the final merge renormalization.
__device__ __forceinline__ void upd_row(float p, const f4 (&R)[4], float& m,
                                        float& lsum, f4 (&acc)[4]) {
  if (p > m + 8.f) {  // wave-uniform (p is reduced), no divergence
    const float sc = __expf(m - p);
    lsum *= sc;
#pragma unroll
    for (int i = 0; i < 4; ++i) acc[i] *= sc;
    m = p;
  }
  const float w = __expf(p - m);
  lsum += w;
#pragma unroll
  for (int i = 0; i < 4; ++i) {
    acc[i].x = fmaf(w, R[i].x, acc[i].x);
    acc[i].y = fmaf(w, R[i].y, acc[i].y);
    acc[i].z = fmaf(w, R[i].z, acc[i].z);
    acc[i].w = fmaf(w, R[i].w, acc[i].w);
  }
}

// Row-interleaved mapping: wave-local row r -> block row (r*WPB_ + wave).
// The block's 4 waves advance through ONE contiguous 512-KB region as a
// single ~32-KB moving window (DRAM row-buffer locality: 512 device-wide
// streams instead of 2048). Coalescing per instruction unchanged.
#define LOADROW(dst, r)                                  \
  _Pragma("unroll") for (int i = 0; i < 4; ++i) dst[i] = \
      rp[(size_t)((r) * WPB_ + wave) * 256 + lane + 64 * i];

// ---------------------------------------------------------------------------
// Kernel 2 (fused, one pass over hs): wave-per-32-rows in registers, no
// barriers in the streaming loop; two row buffers (A,B rotate); 4
// wave-partials merged in-block via LDS -> ONE (m,l,ctx[1024]) per block.
// ---------------------------------------------------------------------------
__global__ __launch_bounds__(256) void fused_score_ctx_kernel(
    const float* __restrict__ hs, const float* __restrict__ v,
    float* __restrict__ pm, float* __restrict__ pl,
    float* __restrict__ pctx) {
  const int b = blockIdx.y;
  const int wave = threadIdx.x >> 6;
  const int lane = threadIdx.x & 63;

  const f4* vb = (const f4*)(v + (size_t)b * H_);
  f4 vreg[4];
#pragma unroll
  for (int i = 0; i < 4; ++i) vreg[i] = vb[lane + 64 * i];

  // block's shared 128-row region
  const f4* rp =
      (const f4*)(hs + ((size_t)b * T_ + (size_t)blockIdx.x * BROWS_) * H_);

  f4 A[4], Bv[4];
  LOADROW(A, 0);
  LOADROW(Bv, 1);

  float m = -1e30f, lsum = 0.f;
  f4 acc[4] = {{0, 0, 0, 0}, {0, 0, 0, 0}, {0, 0, 0, 0}, {0, 0, 0, 0}};

#pragma unroll
  for (int rr = 0; rr < RW_; rr += 2) {
    float pA = dot16(A, vreg), pB = dot16(Bv, vreg);
#pragma unroll
    for (int off = 32; off > 0; off >>= 1) {  // two interleaved chains
      pA += __shfl_xor(pA, off);
      pB += __shfl_xor(pB, off);
    }
    upd_row(pA, A, m, lsum, acc);
    if (rr + 2 < RW_) LOADROW(A, rr + 2);  // refill A while B is consumed
    upd_row(pB, Bv, m, lsum, acc);
    if (rr + 3 < RW_) LOADROW(Bv, rr + 3);
  }

  // in-block merge of the 4 wave-partials (16.4 KB LDS)
  __shared__ f4 sacc[WPB_][256];
  __shared__ float sm[WPB_], sl[WPB_];
#pragma unroll
  for (int i = 0; i < 4; ++i) sacc[wave][lane + 64 * i] = acc[i];
  if (lane == 0) { sm[wave] = m; sl[wave] = lsum; }
  __syncthreads();

  const int tid = threadIdx.x;
  float Mb = fmaxf(fmaxf(sm[0], sm[1]), fmaxf(sm[2], sm[3]));
  float f0 = __expf(sm[0] - Mb), f1 = __expf(sm[1] - Mb);
  float f2 = __expf(sm[2] - Mb), f3 = __expf(sm[3] - Mb);
  float Lb = sl[0] * f0 + sl[1] * f1 + sl[2] * f2 + sl[3] * f3;
  f4 r = f0 * sacc[0][tid] + f1 * sacc[1][tid] + f2 * sacc[2][tid] +
         f3 * sacc[3][tid];

  const int pidx = b * NPART_ + blockIdx.x;
  if (tid == 0) { pm[pidx] = Mb; pl[pidx] = Lb; }
  ((f4*)pctx)[(size_t)pidx * 256 + tid] = r;
}

// ---------------------------------------------------------------------------
// Kernel 3: merge partials + output GEMV partials, fused.
// grid = (B, JC) = 512 blocks x 128 thr. jc<8: merge the needed 128-float
// ctx slice from the 16 block-partials; jc>=8: slice of h_t. Then
// opart[b,jc,d] = sum_i pre[i] * Wout[jc*128+i, d].
// ---------------------------------------------------------------------------
__global__ __launch_bounds__(128) void out_partial_kernel(
    const float* __restrict__ pm, const float* __restrict__ pl,
    const float* __restrict__ pctx, const float* __restrict__ hs,
    const float* __restrict__ Wout, float* __restrict__ opart) {
  const int b = blockIdx.x;
  const int jc = blockIdx.y;
  const int d = threadIdx.x;  // 0..127
  __shared__ float pre[JCH_];
  if (jc < 8) {
    const float* pmb = pm + b * NPART_;
    const float* plb = pl + b * NPART_;
    float M = -1e30f;
#pragma unroll
    for (int j = 0; j < NPART_; ++j) M = fmaxf(M, pmb[j]);
    float L = 0.f;
#pragma unroll
    for (int j = 0; j < NPART_; ++j) L += plb[j] * __expf(pmb[j] - M);
    float a = 0.f;
    const int h = jc * JCH_ + d;
#pragma unroll 4
    for (int j = 0; j < NPART_; ++j)
      a += __expf(pmb[j] - M) * pctx[((size_t)(b * NPART_ + j)) * H_ + h];
    pre[d] = a / L;
  } else {
    pre[d] = hs[((size_t)b * T_ + (T_ - 1)) * H_ + (jc - 8) * JCH_ + d];
  }
  __syncthreads();
  float acc = 0.f;
#pragma unroll 8
  for (int i = 0; i < JCH_; ++i)
    acc += pre[i] * Wout[((size_t)(jc * JCH_ + i)) * DOUT_ + d];
  opart[((size_t)b * JC_ + jc) * DOUT_ + d] = acc;
}

// ---------------------------------------------------------------------------
// Kernel 4: out[b,d] = tanh( sum_jc opart[b,jc,d] )
// ---------------------------------------------------------------------------
__global__ __launch_bounds__(128) void out_reduce_kernel(
    const float* __restrict__ opart, float* __restrict__ out) {
  const int b = blockIdx.x;
  const int d = threadIdx.x;
  float acc = 0.f;
#pragma unroll
  for (int jc = 0; jc < JC_; ++jc)
    acc += opart[((size_t)b * JC_ + jc) * DOUT_ + d];
  out[(size_t)b * DOUT_ + d] = tanhf(acc);
}

extern "C" void kernel_launch(void* const* d_in, const int* in_sizes, int n_in,
                              void* d_out, int out_size, void* d_ws, size_t ws_size,
                              hipStream_t stream) {
  const float* hs = (const float*)d_in[0];      // (B, T, H)
  const float* Wscore = (const float*)d_in[1];  // (H, H)
  const float* Wout = (const float*)d_in[2];    // (2H, DOUT)
  float* out = (float*)d_out;                   // (B, DOUT)

  float* ws = (float*)d_ws;
  float* v = ws;                                // B*H        = 32768
  float* pm = v + B_ * H_;                      // B*16       = 512
  float* pl = pm + B_ * NPART_;                 // B*16       = 512
  float* pctx = pl + B_ * NPART_;               // B*16*H     = 524288
  float* opart = pctx + (size_t)B_ * NPART_ * H_;  // B*JC*DOUT = 65536

  compute_v_kernel<<<dim3(H_), 256, 0, stream>>>(hs, Wscore, v);
  fused_score_ctx_kernel<<<dim3(FBLK_, B_), 256, 0, stream>>>(hs, v, pm, pl, pctx);
  out_partial_kernel<<<dim3(B_, JC_), 128, 0, stream>>>(pm, pl, pctx, hs, Wout, opart);
  out_reduce_kernel<<<dim3(B_), 128, 0, stream>>>(opart, out);
}

// Round 16
// 60.298 us; speedup vs baseline: 1.3739x; 1.0126x over previous
//
#include <hip/hip_runtime.h>
#include <hip/hip_bf16.h>
#include <math.h>

#define B_ 32
#define T_ 2048
#define H_ 1024
#define DOUT_ 128

#define RW_ 32                     // rows per wave (fused pass)
#define WPB_ 8                     // waves per block (512 thr)
#define BROWS_ (RW_ * WPB_)        // 256 rows per block (shared window)
#define FBLK_ (T_ / BROWS_)        // 8 blocks per batch
#define NPART_ FBLK_               // one merged partial per block

#define JC_ 16                     // j-chunks for output GEMV
#define JCH_ (2 * H_ / JC_)        // 128 j per chunk

typedef float f4 __attribute__((ext_vector_type(4)));

// ---------------------------------------------------------------------------
// Kernel 1: v[b,h] = dot(W_score[h,:], h_t[b,:]).
// grid = H blocks x 256 thr (4 waves); wave w handles batches 8w..8w+7.
// ---------------------------------------------------------------------------
__global__ __launch_bounds__(256) void compute_v_kernel(
    const float* __restrict__ hs, const float* __restrict__ Wscore,
    float* __restrict__ v) {
  const int h = blockIdx.x;
  const int tid = threadIdx.x;
  const int wave = tid >> 6, lane = tid & 63;
  const f4* wrow = (const f4*)(Wscore + (size_t)h * H_);
  f4 w4[4];
#pragma unroll
  for (int i = 0; i < 4; ++i) w4[i] = wrow[lane + 64 * i];
#pragma unroll
  for (int bb = 0; bb < 8; ++bb) {
    const int b = wave * 8 + bb;
    const f4* ht = (const f4*)(hs + ((size_t)b * T_ + (T_ - 1)) * H_);
    float acc = 0.f;
#pragma unroll
    for (int i = 0; i < 4; ++i) {
      f4 a = ht[lane + 64 * i];
      acc += a.x * w4[i].x + a.y * w4[i].y + a.z * w4[i].z + a.w * w4[i].w;
    }
#pragma unroll
    for (int off = 32; off > 0; off >>= 1) acc += __shfl_down(acc, off);
    if (lane == 0) v[b * H_ + h] = acc;
  }
}

// ---------------------------------------------------------------------------
// Fused pass helpers: wave-private register-resident online softmax + ctx.
// Lane l owns f4 slots {l, l+64, l+128, l+192} of each 1024-float row.
// ---------------------------------------------------------------------------
__device__ __forceinline__ float dot16(const f4 (&A)[4], const f4 (&V)[4]) {
  float p = 0.f;
#pragma unroll
  for (int i = 0; i < 4; ++i)
    p += A[i].x * V[i].x + A[i].y * V[i].y + A[i].z * V[i].z + A[i].w * V[i].w;
  return p;
}

// defer-max (T13): rescale only when the new score exceeds m by >8; weights
// then bounded by e^8 — exact after the final merge renormalization.
__device__ __forceinline__ void upd_row(float p, const f4 (&R)[4], float& m,
                                        float& lsum, f4 (&acc)[4]) {
  if (p > m + 8.f) {  // wave-uniform (p is reduced), no divergence
    const float sc = __expf(m - p);
    lsum *= sc;
#pragma unroll
    for (int i = 0; i < 4; ++i) acc[i] *= sc;
    m = p;
  }
  const float w = __expf(p - m);
  lsum += w;
#pragma unroll
  for (int i = 0; i < 4; ++i) {
    acc[i].x = fmaf(w, R[i].x, acc[i].x);
    acc[i].y = fmaf(w, R[i].y, acc[i].y);
    acc[i].z = fmaf(w, R[i].z, acc[i].z);
    acc[i].w = fmaf(w, R[i].w, acc[i].w);
  }
}

// Row-interleaved mapping: wave-local row r -> block row (r*WPB_ + wave).
// The block's 8 waves advance through ONE contiguous 1-MB region as a
// single moving window (256 device-wide streams; R15's 512-stream version
// bought -4.5us over 2048). Coalescing per instruction unchanged.
#define LOADROW(dst, r)                                  \
  _Pragma("unroll") for (int i = 0; i < 4; ++i) dst[i] = \
      rp[(size_t)((r) * WPB_ + wave) * 256 + lane + 64 * i];

// ---------------------------------------------------------------------------
// Kernel 2 (fused, one pass over hs): wave-per-32-rows in registers, no
// barriers in the streaming loop; two row buffers (A,B rotate); 8
// wave-partials merged in-block via LDS -> ONE (m,l,ctx[1024]) per block.
// ---------------------------------------------------------------------------
__global__ __launch_bounds__(512) void fused_score_ctx_kernel(
    const float* __restrict__ hs, const float* __restrict__ v,
    float* __restrict__ pm, float* __restrict__ pl,
    float* __restrict__ pctx) {
  const int b = blockIdx.y;
  const int wave = threadIdx.x >> 6;
  const int lane = threadIdx.x & 63;

  const f4* vb = (const f4*)(v + (size_t)b * H_);
  f4 vreg[4];
#pragma unroll
  for (int i = 0; i < 4; ++i) vreg[i] = vb[lane + 64 * i];

  // block's shared 256-row region
  const f4* rp =
      (const f4*)(hs + ((size_t)b * T_ + (size_t)blockIdx.x * BROWS_) * H_);

  f4 A[4], Bv[4];
  LOADROW(A, 0);
  LOADROW(Bv, 1);

  float m = -1e30f, lsum = 0.f;
  f4 acc[4] = {{0, 0, 0, 0}, {0, 0, 0, 0}, {0, 0, 0, 0}, {0, 0, 0, 0}};

#pragma unroll
  for (int rr = 0; rr < RW_; rr += 2) {
    float pA = dot16(A, vreg), pB = dot16(Bv, vreg);
#pragma unroll
    for (int off = 32; off > 0; off >>= 1) {  // two interleaved chains
      pA += __shfl_xor(pA, off);
      pB += __shfl_xor(pB, off);
    }
    upd_row(pA, A, m, lsum, acc);
    if (rr + 2 < RW_) LOADROW(A, rr + 2);  // refill A while B is consumed
    upd_row(pB, Bv, m, lsum, acc);
    if (rr + 3 < RW_) LOADROW(Bv, rr + 3);
  }

  // in-block merge of the 8 wave-partials (32.8 KB LDS)
  __shared__ f4 sacc[WPB_][256];
  __shared__ float sm[WPB_], sl[WPB_];
#pragma unroll
  for (int i = 0; i < 4; ++i) sacc[wave][lane + 64 * i] = acc[i];
  if (lane == 0) { sm[wave] = m; sl[wave] = lsum; }
  __syncthreads();

  const int tid = threadIdx.x;
  if (tid < 256) {
    float Mb = sm[0];
#pragma unroll
    for (int w = 1; w < WPB_; ++w) Mb = fmaxf(Mb, sm[w]);
    float Lb = 0.f;
    f4 r = {0, 0, 0, 0};
#pragma unroll
    for (int w = 0; w < WPB_; ++w) {
      const float f = __expf(sm[w] - Mb);
      Lb += f * sl[w];
      r += f * sacc[w][tid];
    }
    const int pidx = b * NPART_ + blockIdx.x;
    if (tid == 0) { pm[pidx] = Mb; pl[pidx] = Lb; }
    ((f4*)pctx)[(size_t)pidx * 256 + tid] = r;
  }
}

// ---------------------------------------------------------------------------
// Kernel 3: merge partials + output GEMV partials, fused.
// grid = (B, JC) = 512 blocks x 128 thr. jc<8: merge the needed 128-float
// ctx slice from the 8 block-partials; jc>=8: slice of h_t. Then
// opart[b,jc,d] = sum_i pre[i] * Wout[jc*128+i, d].
// ---------------------------------------------------------------------------
__global__ __launch_bounds__(128) void out_partial_kernel(
    const float* __restrict__ pm, const float* __restrict__ pl,
    const float* __restrict__ pctx, const float* __restrict__ hs,
    const float* __restrict__ Wout, float* __restrict__ opart) {
  const int b = blockIdx.x;
  const int jc = blockIdx.y;
  const int d = threadIdx.x;  // 0..127
  __shared__ float pre[JCH_];
  if (jc < 8) {
    const float* pmb = pm + b * NPART_;
    const float* plb = pl + b * NPART_;
    float M = -1e30f;
#pragma unroll
    for (int j = 0; j < NPART_; ++j) M = fmaxf(M, pmb[j]);
    float L = 0.f;
#pragma unroll
    for (int j = 0; j < NPART_; ++j) L += plb[j] * __expf(pmb[j] - M);
    float a = 0.f;
    const int h = jc * JCH_ + d;
#pragma unroll 4
    for (int j = 0; j < NPART_; ++j)
      a += __expf(pmb[j] - M) * pctx[((size_t)(b * NPART_ + j)) * H_ + h];
    pre[d] = a / L;
  } else {
    pre[d] = hs[((size_t)b * T_ + (T_ - 1)) * H_ + (jc - 8) * JCH_ + d];
  }
  __syncthreads();
  float acc = 0.f;
#pragma unroll 8
  for (int i = 0; i < JCH_; ++i)
    acc += pre[i] * Wout[((size_t)(jc * JCH_ + i)) * DOUT_ + d];
  opart[((size_t)b * JC_ + jc) * DOUT_ + d] = acc;
}

// ---------------------------------------------------------------------------
// Kernel 4: out[b,d] = tanh( sum_jc opart[b,jc,d] )
// ---------------------------------------------------------------------------
__global__ __launch_bounds__(128) void out_reduce_kernel(
    const float* __restrict__ opart, float* __restrict__ out) {
  const int b = blockIdx.x;
  const int d = threadIdx.x;
  float acc = 0.f;
#pragma unroll
  for (int jc = 0; jc < JC_; ++jc)
    acc += opart[((size_t)b * JC_ + jc) * DOUT_ + d];
  out[(size_t)b * DOUT_ + d] = tanhf(acc);
}

extern "C" void kernel_launch(void* const* d_in, const int* in_sizes, int n_in,
                              void* d_out, int out_size, void* d_ws, size_t ws_size,
                              hipStream_t stream) {
  const float* hs = (const float*)d_in[0];      // (B, T, H)
  const float* Wscore = (const float*)d_in[1];  // (H, H)
  const float* Wout = (const float*)d_in[2];    // (2H, DOUT)
  float* out = (float*)d_out;                   // (B, DOUT)

  float* ws = (float*)d_ws;
  float* v = ws;                                // B*H        = 32768
  float* pm = v + B_ * H_;                      // B*8        = 256
  float* pl = pm + B_ * NPART_;                 // B*8        = 256
  float* pctx = pl + B_ * NPART_;               // B*8*H      = 262144
  float* opart = pctx + (size_t)B_ * NPART_ * H_;  // B*JC*DOUT = 65536

  compute_v_kernel<<<dim3(H_), 256, 0, stream>>>(hs, Wscore, v);
  fused_score_ctx_kernel<<<dim3(FBLK_, B_), 512, 0, stream>>>(hs, v, pm, pl, pctx);
  out_partial_kernel<<<dim3(B_, JC_), 128, 0, stream>>>(pm, pl, pctx, hs, Wout, opart);
  out_reduce_kernel<<<dim3(B_), 128, 0, stream>>>(opart, out);
}